// Round 6
// baseline (381.652 us; speedup 1.0000x reference)
//
#include <hip/hip_runtime.h>

// Axial 7x7 attention, fused. N=512, GRID=7, Cq=64, Cv=512, B=3584.
// qH,qW:(B,7,64) kH,kW:(B,64,7) vH,vW:(B,512,7) out:(N,512,7,7) fp32
// R6: phase D hand-unrolled in plain C++ (no macros): 49 named scalar
// accumulators -> guaranteed VGPR residency. R3/R4 left acc[49] in scratch
// (dynamic indices survived into the backend; 879 MB HBM scratch traffic).

#define NEGINF (-1e20f)

constexpr int QK_SLICE = 7 * 7 * 64;   // 3136
constexpr int V_SLICE  = 7 * 512 * 7;  // 25088

// LDS floats:
//  [0,14336)    V: v slab-pair double buffer (2 x 7168); aliases qk staging
//               (qHs 3332|kHs 3192|qWs 3332|kWs 3192 = 13048) and the
//               writeback buffer 256x51 = 13056
//  [14336,15120) P logits 49x16
//  [15120,15512) pHs 49x8  (padded prob rows, H part)
//  [15512,15904) pWs 49x8
// total 15904 fl = 63616 B -> 2 blocks/CU

__device__ __forceinline__ void load_lds16(const float* g, float* l) {
    __builtin_amdgcn_global_load_lds(
        (const __attribute__((address_space(1))) unsigned int*)g,
        (__attribute__((address_space(3))) unsigned int*)l, 16, 0, 0);
}

// stage slab-pair ip (vH slab + vW slab, 7168 floats) into buffer ip&1
__device__ __forceinline__ void prefetch_slab(const float* vHn, const float* vWn,
                                              int ip, float* V, int t) {
    const float* sH = vHn + ip * 3584;
    const float* sW = vWn + ip * 3584;
    float* dst = V + (ip & 1) * 7168;
    load_lds16(sH + t * 4, dst + t * 4);
    int id = t + 512;
    const float* g = (id < 896) ? sH + id * 4 : sW + (id - 896) * 4;
    load_lds16(g, dst + id * 4);
    load_lds16(sW + (t + 128) * 4, dst + (t + 1024) * 4);
    if (t < 256) load_lds16(sW + (t + 640) * 4, dst + (t + 1536) * 4);
}

// dot(prob_row[0..6], x0..x6); prob row is 8-padded, wave-uniform LDS address
__device__ __forceinline__ float pdot(const float* p, float x0, float x1,
                                      float x2, float x3, float x4, float x5,
                                      float x6) {
    float4 p0 = *(const float4*)p;
    float4 p1 = *(const float4*)(p + 4);
    return p0.x * x0 + p0.y * x1 + p0.z * x2 + p0.w * x3 +
           p1.x * x4 + p1.y * x5 + p1.z * x6;
}

__global__ __launch_bounds__(512, 4) void fused_axial(
    const float* __restrict__ qH, const float* __restrict__ kH,
    const float* __restrict__ vH, const float* __restrict__ qW,
    const float* __restrict__ kW, const float* __restrict__ vW,
    float* __restrict__ out)
{
    __shared__ float sm[15904];
    float* V   = sm;
    float* P   = sm + 14336;
    float* pHs = sm + 15120;
    float* pWs = sm + 15512;

    float* qHs = sm;
    float* kHs = sm + 3332;
    float* qWs = sm + 6524;
    float* kWs = sm + 9856;

    const int n = blockIdx.x;
    const int t = threadIdx.x;

    // ---- Phase A: stage q/k (coalesced float4) ----
    {
        const float* srcQH = qH + n * QK_SLICE;
        const float* srcKH = kH + n * QK_SLICE;
        const float* srcQW = qW + n * QK_SLICE;
        const float* srcKW = kW + n * QK_SLICE;
        for (int it = t; it < 784; it += 512) {
            int wh = it >> 4;
            int c  = (it & 15) << 2;
            float4 v0 = ((const float4*)srcQH)[it];
            *(float4*)(qHs + wh * 68 + c) = v0;
            float4 v1 = ((const float4*)srcQW)[it];
            *(float4*)(qWs + wh * 68 + c) = v1;
            int w = it / 112;
            int r = (it - w * 112) << 2;
            float4 v2 = ((const float4*)srcKH)[it];
            *(float4*)(kHs + w * 456 + r) = v2;
            float4 v3 = ((const float4*)srcKW)[it];
            *(float4*)(kWs + w * 456 + r) = v3;
        }
    }
    __syncthreads();

    // ---- Phase B: 686 dots -> logits in P ----
    for (int d = t; d < 686; d += 512) {
        const bool isH = d < 343;
        int dd = isH ? d : d - 343;
        int a   = dd / 49;
        int rem = dd - a * 49;
        int b   = rem / 7;
        int j   = rem - b * 7;
        const float* qrow  = (isH ? qHs : qWs) + (a * 7 + b) * 68;
        const float* kbase = (isH ? kHs : kWs) + a * 456 + j;
        float e = 0.f;
        #pragma unroll
        for (int c = 0; c < 64; c += 4) {
            float4 qv = *(const float4*)(qrow + c);
            e += qv.x * kbase[c * 7];
            e += qv.y * kbase[c * 7 + 7];
            e += qv.z * kbase[c * 7 + 14];
            e += qv.w * kbase[c * 7 + 21];
        }
        if (isH) {
            if (b == j) e = NEGINF;
            P[(b * 7 + a) * 16 + j] = e;
        } else {
            P[(a * 7 + b) * 16 + 7 + j] = e;
        }
    }
    __syncthreads();   // qk region dead from here on

    const float* vHn = vH + n * V_SLICE;
    const float* vWn = vW + n * V_SLICE;

    // prefetch slab-pair 0 (latency hidden behind softmax + barrier)
    prefetch_slab(vHn, vWn, 0, V, t);

    // ---- Phase C: softmax, write padded prob tables ----
    if (t < 49) {
        float* row = P + t * 16;
        float l[14];
        float m = -3.4e38f;
        #pragma unroll
        for (int k = 0; k < 14; ++k) { l[k] = row[k]; m = fmaxf(m, l[k]); }
        float s = 0.f;
        #pragma unroll
        for (int k = 0; k < 14; ++k) { l[k] = __expf(l[k] - m); s += l[k]; }
        float inv = 1.f / s;
        #pragma unroll
        for (int j = 0; j < 7; ++j) {
            pHs[t * 8 + j] = l[j] * inv;
            pWs[t * 8 + j] = l[7 + j] * inv;
        }
    }
    __syncthreads();   // probs ready + slab0 landed

    // ---- Phase D: thread t owns channel c=t; 49 scalar accumulators ----
    // out[c,h,w]: slab i adds pH[h,i].vh to a{h}{i} and pW[i,w].vw to a{i}{w}.
    // pHs offset for (h,i) = h*56+i*8; pWs offset for (i,w) = i*56+w*8.
    float a00=0.f,a01=0.f,a02=0.f,a03=0.f,a04=0.f,a05=0.f,a06=0.f;
    float a10=0.f,a11=0.f,a12=0.f,a13=0.f,a14=0.f,a15=0.f,a16=0.f;
    float a20=0.f,a21=0.f,a22=0.f,a23=0.f,a24=0.f,a25=0.f,a26=0.f;
    float a30=0.f,a31=0.f,a32=0.f,a33=0.f,a34=0.f,a35=0.f,a36=0.f;
    float a40=0.f,a41=0.f,a42=0.f,a43=0.f,a44=0.f,a45=0.f,a46=0.f;
    float a50=0.f,a51=0.f,a52=0.f,a53=0.f,a54=0.f,a55=0.f,a56=0.f;
    float a60=0.f,a61=0.f,a62=0.f,a63=0.f,a64=0.f,a65=0.f,a66=0.f;

    { // slab 0 (buf 0)
        prefetch_slab(vHn, vWn, 1, V, t);
        const float* hr = V + t * 7;
        const float* wr = V + 3584 + t * 7;
        float h0=hr[0],h1=hr[1],h2=hr[2],h3=hr[3],h4=hr[4],h5=hr[5],h6=hr[6];
        float w0=wr[0],w1=wr[1],w2=wr[2],w3=wr[3],w4=wr[4],w5=wr[5],w6=wr[6];
        a00 += pdot(pHs +   0, h0,h1,h2,h3,h4,h5,h6);
        a10 += pdot(pHs +  56, h0,h1,h2,h3,h4,h5,h6);
        a20 += pdot(pHs + 112, h0,h1,h2,h3,h4,h5,h6);
        a30 += pdot(pHs + 168, h0,h1,h2,h3,h4,h5,h6);
        a40 += pdot(pHs + 224, h0,h1,h2,h3,h4,h5,h6);
        a50 += pdot(pHs + 280, h0,h1,h2,h3,h4,h5,h6);
        a60 += pdot(pHs + 336, h0,h1,h2,h3,h4,h5,h6);
        a00 += pdot(pWs +   0, w0,w1,w2,w3,w4,w5,w6);
        a01 += pdot(pWs +   8, w0,w1,w2,w3,w4,w5,w6);
        a02 += pdot(pWs +  16, w0,w1,w2,w3,w4,w5,w6);
        a03 += pdot(pWs +  24, w0,w1,w2,w3,w4,w5,w6);
        a04 += pdot(pWs +  32, w0,w1,w2,w3,w4,w5,w6);
        a05 += pdot(pWs +  40, w0,w1,w2,w3,w4,w5,w6);
        a06 += pdot(pWs +  48, w0,w1,w2,w3,w4,w5,w6);
    }
    __syncthreads();
    { // slab 1 (buf 1)
        prefetch_slab(vHn, vWn, 2, V, t);
        const float* hr = V + 7168 + t * 7;
        const float* wr = V + 7168 + 3584 + t * 7;
        float h0=hr[0],h1=hr[1],h2=hr[2],h3=hr[3],h4=hr[4],h5=hr[5],h6=hr[6];
        float w0=wr[0],w1=wr[1],w2=wr[2],w3=wr[3],w4=wr[4],w5=wr[5],w6=wr[6];
        a01 += pdot(pHs +   8, h0,h1,h2,h3,h4,h5,h6);
        a11 += pdot(pHs +  64, h0,h1,h2,h3,h4,h5,h6);
        a21 += pdot(pHs + 120, h0,h1,h2,h3,h4,h5,h6);
        a31 += pdot(pHs + 176, h0,h1,h2,h3,h4,h5,h6);
        a41 += pdot(pHs + 232, h0,h1,h2,h3,h4,h5,h6);
        a51 += pdot(pHs + 288, h0,h1,h2,h3,h4,h5,h6);
        a61 += pdot(pHs + 344, h0,h1,h2,h3,h4,h5,h6);
        a10 += pdot(pWs +  56, w0,w1,w2,w3,w4,w5,w6);
        a11 += pdot(pWs +  64, w0,w1,w2,w3,w4,w5,w6);
        a12 += pdot(pWs +  72, w0,w1,w2,w3,w4,w5,w6);
        a13 += pdot(pWs +  80, w0,w1,w2,w3,w4,w5,w6);
        a14 += pdot(pWs +  88, w0,w1,w2,w3,w4,w5,w6);
        a15 += pdot(pWs +  96, w0,w1,w2,w3,w4,w5,w6);
        a16 += pdot(pWs + 104, w0,w1,w2,w3,w4,w5,w6);
    }
    __syncthreads();
    { // slab 2 (buf 0)
        prefetch_slab(vHn, vWn, 3, V, t);
        const float* hr = V + t * 7;
        const float* wr = V + 3584 + t * 7;
        float h0=hr[0],h1=hr[1],h2=hr[2],h3=hr[3],h4=hr[4],h5=hr[5],h6=hr[6];
        float w0=wr[0],w1=wr[1],w2=wr[2],w3=wr[3],w4=wr[4],w5=wr[5],w6=wr[6];
        a02 += pdot(pHs +  16, h0,h1,h2,h3,h4,h5,h6);
        a12 += pdot(pHs +  72, h0,h1,h2,h3,h4,h5,h6);
        a22 += pdot(pHs + 128, h0,h1,h2,h3,h4,h5,h6);
        a32 += pdot(pHs + 184, h0,h1,h2,h3,h4,h5,h6);
        a42 += pdot(pHs + 240, h0,h1,h2,h3,h4,h5,h6);
        a52 += pdot(pHs + 296, h0,h1,h2,h3,h4,h5,h6);
        a62 += pdot(pHs + 352, h0,h1,h2,h3,h4,h5,h6);
        a20 += pdot(pWs + 112, w0,w1,w2,w3,w4,w5,w6);
        a21 += pdot(pWs + 120, w0,w1,w2,w3,w4,w5,w6);
        a22 += pdot(pWs + 128, w0,w1,w2,w3,w4,w5,w6);
        a23 += pdot(pWs + 136, w0,w1,w2,w3,w4,w5,w6);
        a24 += pdot(pWs + 144, w0,w1,w2,w3,w4,w5,w6);
        a25 += pdot(pWs + 152, w0,w1,w2,w3,w4,w5,w6);
        a26 += pdot(pWs + 160, w0,w1,w2,w3,w4,w5,w6);
    }
    __syncthreads();
    { // slab 3 (buf 1)
        prefetch_slab(vHn, vWn, 4, V, t);
        const float* hr = V + 7168 + t * 7;
        const float* wr = V + 7168 + 3584 + t * 7;
        float h0=hr[0],h1=hr[1],h2=hr[2],h3=hr[3],h4=hr[4],h5=hr[5],h6=hr[6];
        float w0=wr[0],w1=wr[1],w2=wr[2],w3=wr[3],w4=wr[4],w5=wr[5],w6=wr[6];
        a03 += pdot(pHs +  24, h0,h1,h2,h3,h4,h5,h6);
        a13 += pdot(pHs +  80, h0,h1,h2,h3,h4,h5,h6);
        a23 += pdot(pHs + 136, h0,h1,h2,h3,h4,h5,h6);
        a33 += pdot(pHs + 192, h0,h1,h2,h3,h4,h5,h6);
        a43 += pdot(pHs + 248, h0,h1,h2,h3,h4,h5,h6);
        a53 += pdot(pHs + 304, h0,h1,h2,h3,h4,h5,h6);
        a63 += pdot(pHs + 360, h0,h1,h2,h3,h4,h5,h6);
        a30 += pdot(pWs + 168, w0,w1,w2,w3,w4,w5,w6);
        a31 += pdot(pWs + 176, w0,w1,w2,w3,w4,w5,w6);
        a32 += pdot(pWs + 184, w0,w1,w2,w3,w4,w5,w6);
        a33 += pdot(pWs + 192, w0,w1,w2,w3,w4,w5,w6);
        a34 += pdot(pWs + 200, w0,w1,w2,w3,w4,w5,w6);
        a35 += pdot(pWs + 208, w0,w1,w2,w3,w4,w5,w6);
        a36 += pdot(pWs + 216, w0,w1,w2,w3,w4,w5,w6);
    }
    __syncthreads();
    { // slab 4 (buf 0)
        prefetch_slab(vHn, vWn, 5, V, t);
        const float* hr = V + t * 7;
        const float* wr = V + 3584 + t * 7;
        float h0=hr[0],h1=hr[1],h2=hr[2],h3=hr[3],h4=hr[4],h5=hr[5],h6=hr[6];
        float w0=wr[0],w1=wr[1],w2=wr[2],w3=wr[3],w4=wr[4],w5=wr[5],w6=wr[6];
        a04 += pdot(pHs +  32, h0,h1,h2,h3,h4,h5,h6);
        a14 += pdot(pHs +  88, h0,h1,h2,h3,h4,h5,h6);
        a24 += pdot(pHs + 144, h0,h1,h2,h3,h4,h5,h6);
        a34 += pdot(pHs + 200, h0,h1,h2,h3,h4,h5,h6);
        a44 += pdot(pHs + 256, h0,h1,h2,h3,h4,h5,h6);
        a54 += pdot(pHs + 312, h0,h1,h2,h3,h4,h5,h6);
        a64 += pdot(pHs + 368, h0,h1,h2,h3,h4,h5,h6);
        a40 += pdot(pWs + 224, w0,w1,w2,w3,w4,w5,w6);
        a41 += pdot(pWs + 232, w0,w1,w2,w3,w4,w5,w6);
        a42 += pdot(pWs + 240, w0,w1,w2,w3,w4,w5,w6);
        a43 += pdot(pWs + 248, w0,w1,w2,w3,w4,w5,w6);
        a44 += pdot(pWs + 256, w0,w1,w2,w3,w4,w5,w6);
        a45 += pdot(pWs + 264, w0,w1,w2,w3,w4,w5,w6);
        a46 += pdot(pWs + 272, w0,w1,w2,w3,w4,w5,w6);
    }
    __syncthreads();
    { // slab 5 (buf 1)
        prefetch_slab(vHn, vWn, 6, V, t);
        const float* hr = V + 7168 + t * 7;
        const float* wr = V + 7168 + 3584 + t * 7;
        float h0=hr[0],h1=hr[1],h2=hr[2],h3=hr[3],h4=hr[4],h5=hr[5],h6=hr[6];
        float w0=wr[0],w1=wr[1],w2=wr[2],w3=wr[3],w4=wr[4],w5=wr[5],w6=wr[6];
        a05 += pdot(pHs +  40, h0,h1,h2,h3,h4,h5,h6);
        a15 += pdot(pHs +  96, h0,h1,h2,h3,h4,h5,h6);
        a25 += pdot(pHs + 152, h0,h1,h2,h3,h4,h5,h6);
        a35 += pdot(pHs + 208, h0,h1,h2,h3,h4,h5,h6);
        a45 += pdot(pHs + 264, h0,h1,h2,h3,h4,h5,h6);
        a55 += pdot(pHs + 320, h0,h1,h2,h3,h4,h5,h6);
        a65 += pdot(pHs + 376, h0,h1,h2,h3,h4,h5,h6);
        a50 += pdot(pWs + 280, w0,w1,w2,w3,w4,w5,w6);
        a51 += pdot(pWs + 288, w0,w1,w2,w3,w4,w5,w6);
        a52 += pdot(pWs + 296, w0,w1,w2,w3,w4,w5,w6);
        a53 += pdot(pWs + 304, w0,w1,w2,w3,w4,w5,w6);
        a54 += pdot(pWs + 312, w0,w1,w2,w3,w4,w5,w6);
        a55 += pdot(pWs + 320, w0,w1,w2,w3,w4,w5,w6);
        a56 += pdot(pWs + 328, w0,w1,w2,w3,w4,w5,w6);
    }
    __syncthreads();
    { // slab 6 (buf 0)
        const float* hr = V + t * 7;
        const float* wr = V + 3584 + t * 7;
        float h0=hr[0],h1=hr[1],h2=hr[2],h3=hr[3],h4=hr[4],h5=hr[5],h6=hr[6];
        float w0=wr[0],w1=wr[1],w2=wr[2],w3=wr[3],w4=wr[4],w5=wr[5],w6=wr[6];
        a06 += pdot(pHs +  48, h0,h1,h2,h3,h4,h5,h6);
        a16 += pdot(pHs + 104, h0,h1,h2,h3,h4,h5,h6);
        a26 += pdot(pHs + 160, h0,h1,h2,h3,h4,h5,h6);
        a36 += pdot(pHs + 216, h0,h1,h2,h3,h4,h5,h6);
        a46 += pdot(pHs + 272, h0,h1,h2,h3,h4,h5,h6);
        a56 += pdot(pHs + 328, h0,h1,h2,h3,h4,h5,h6);
        a66 += pdot(pHs + 384, h0,h1,h2,h3,h4,h5,h6);
        a60 += pdot(pWs + 336, w0,w1,w2,w3,w4,w5,w6);
        a61 += pdot(pWs + 344, w0,w1,w2,w3,w4,w5,w6);
        a62 += pdot(pWs + 352, w0,w1,w2,w3,w4,w5,w6);
        a63 += pdot(pWs + 360, w0,w1,w2,w3,w4,w5,w6);
        a64 += pdot(pWs + 368, w0,w1,w2,w3,w4,w5,w6);
        a65 += pdot(pWs + 376, w0,w1,w2,w3,w4,w5,w6);
        a66 += pdot(pWs + 384, w0,w1,w2,w3,w4,w5,w6);
    }
    __syncthreads();

    // ---- Phase E: transpose through LDS, coalesced float4 stores ----
    float* outn = out + n * V_SLICE;
    for (int half = 0; half < 2; ++half) {
        if ((t >> 8) == half) {
            float* wb = V + (t & 255) * 51;
            wb[ 0]=a00; wb[ 1]=a01; wb[ 2]=a02; wb[ 3]=a03; wb[ 4]=a04; wb[ 5]=a05; wb[ 6]=a06;
            wb[ 7]=a10; wb[ 8]=a11; wb[ 9]=a12; wb[10]=a13; wb[11]=a14; wb[12]=a15; wb[13]=a16;
            wb[14]=a20; wb[15]=a21; wb[16]=a22; wb[17]=a23; wb[18]=a24; wb[19]=a25; wb[20]=a26;
            wb[21]=a30; wb[22]=a31; wb[23]=a32; wb[24]=a33; wb[25]=a34; wb[26]=a35; wb[27]=a36;
            wb[28]=a40; wb[29]=a41; wb[30]=a42; wb[31]=a43; wb[32]=a44; wb[33]=a45; wb[34]=a46;
            wb[35]=a50; wb[36]=a51; wb[37]=a52; wb[38]=a53; wb[39]=a54; wb[40]=a55; wb[41]=a56;
            wb[42]=a60; wb[43]=a61; wb[44]=a62; wb[45]=a63; wb[46]=a64; wb[47]=a65; wb[48]=a66;
        }
        __syncthreads();
        #pragma unroll
        for (int k = 0; k < 7; ++k) {
            int f4 = t + 512 * k;
            if (f4 < 3136) {
                int f = f4 * 4;
                float4 o;
                #pragma unroll
                for (int u = 0; u < 4; ++u) {
                    int e  = f + u;
                    int c  = e / 49;
                    int hw = e - c * 49;
                    ((float*)&o)[u] = V[c * 51 + hw];
                }
                *(float4*)(outn + half * 12544 + f) = o;
            }
        }
        __syncthreads();
    }
}

extern "C" void kernel_launch(void* const* d_in, const int* in_sizes, int n_in,
                              void* d_out, int out_size, void* d_ws, size_t ws_size,
                              hipStream_t stream) {
    const float* qH = (const float*)d_in[0];
    const float* kH = (const float*)d_in[1];
    const float* vH = (const float*)d_in[2];
    const float* qW = (const float*)d_in[3];
    const float* kW = (const float*)d_in[4];
    const float* vW = (const float*)d_in[5];
    float* out = (float*)d_out;
    fused_axial<<<512, 512, 0, stream>>>(qH, kH, vH, qW, kW, vW, out);
}